// Round 3
// baseline (237.886 us; speedup 1.0000x reference)
//
#include <hip/hip_runtime.h>
#include <math.h>

// TIME_WARPING: not-a-knot cubic spline fit + warped resample, fused.
//
// Math (unchanged from the 230µs harness-verified version): spline system A M = rhs,
//   M1 = y0 - 2 y1 + y2 (exact); M_{S-2} = y_{S-3} - 2 y_{S-2} + y_{S-1} (exact)
//   M0 = 2 M1 - M2;  M_{S-1} = 2 M_{S-2} - M_{S-3}
//   interior: Toeplitz(1,4,1) inverse = conv with G(k) = (-1)^k r^|k|/(2 sqrt 3),
//   r = 2 - sqrt(3), truncated at W=8; boundary image corrections with ghost
//   values v1/vS2.
//
// This round (2nd resubmission — two GPU-acquisition timeouts, never measured):
//  * Pass B (rhs staging in LDS) eliminated: interior M = 19-tap conv of y with
//    H = 6*(G (*) [1,-2,1])  (exact algebraic identity with the old G (*) f conv).
//    Edge threads (j0 < 36 or j0 > SLEN-44) keep the exact f-based path with all
//    boundary conditionals + image corrections, reading y windows with OOB guard.
//    -> LDS drops 49.2 KB -> 32.768 KB exactly => 5 blocks/CU (was 3).
//    -> one fewer __syncthreads (3 -> 2).
//  * Pass D remapped j = t + 256*q (was 4 consecutive per thread): consecutive
//    lanes read consecutive sy/sm elements => ~2 lanes/bank (free) instead of
//    ~stride-4 => 4-8-way conflicts. Stores become scalar but stay perfectly
//    coalesced (256B/wave-instr).
//  * Nontemporal output stores (write-once data; keeps x resident in L3).

#define SLEN 4096
#define WRAD 8
#define BLK  256

typedef float f32x4 __attribute__((ext_vector_type(4)));

__global__ __launch_bounds__(BLK, 5) void time_warp_kernel(
    const float* __restrict__ x,
    const float* __restrict__ scale,
    const int*   __restrict__ apply_mask,
    float* __restrict__ out,
    int C)
{
    __shared__ float sy[SLEN];   // input signal          (16384 B)
    __shared__ float sm[SLEN];   // second derivatives M  (16384 B) => 32768 B total

    const int bid = blockIdx.x;   // = b*C + c
    const int b   = bid / C;
    const int t   = threadIdx.x;
    const float* __restrict__ xin = x   + (size_t)bid * SLEN;
    float*       __restrict__ o   = out + (size_t)bid * SLEN;

    // Per-sample apply decision (block-uniform branch before any barrier).
    if (apply_mask[b] == 0) {
        const f32x4* __restrict__ xi4 = (const f32x4*)xin;
        f32x4*       __restrict__ o4  = (f32x4*)o;
        #pragma unroll
        for (int k = 0; k < 4; ++k) {
            f32x4 v = xi4[t + BLK * k];
            __builtin_nontemporal_store(v, &o4[t + BLK * k]);
        }
        return;
    }

    // ---- stage y into LDS (coalesced float4 -> ds_write_b128) ----
    {
        const float4* __restrict__ xi4 = (const float4*)xin;
        #pragma unroll
        for (int k = 0; k < 4; ++k)
            *(float4*)&sy[4 * (t + BLK * k)] = xi4[t + BLK * k];
    }
    __syncthreads();

    // Green taps (compile-time folded)
    const float r = 0.26794919243112270f;  // 2 - sqrt(3)
    float G[WRAD + 1];
    G[0] = 0.28867513459481287f;           // 1 / (2 sqrt(3))
    #pragma unroll
    for (int k = 1; k <= WRAD; ++k) G[k] = -G[k - 1] * r;
    // H = 6 * (G convolved with [1,-2,1]) : 19-tap direct-on-y kernel
    float Hh[WRAD + 2];
    Hh[0] = 12.0f * (G[1] - G[0]);
    #pragma unroll
    for (int k = 1; k < WRAD; ++k) Hh[k] = 6.0f * (G[k - 1] - 2.0f * G[k] + G[k + 1]);
    Hh[WRAD]     = 6.0f * (G[WRAD - 1] - 2.0f * G[WRAD]);   // G[W+1] = 0
    Hh[WRAD + 1] = 6.0f * G[WRAD];
    const float log2r = -1.8999686269529532f;  // log2(2 - sqrt(3))

    // ---- pass C: M = conv(y), fused rhs (no sf array, no pass B) ----
    #pragma unroll
    for (int s = 0; s < 4; ++s) {
        const int j0 = 4 * t + 1024 * s;
        if (j0 >= 36 && j0 <= SLEN - 44) {
            // interior fast path: pure 19-tap H-conv on y, no conditionals.
            // window y[j0-12 .. j0+15], 7 aligned float4 reads (lane stride 16B,
            // canonical conflict-free ds_read_b128 pattern).
            float wv[28];
            #pragma unroll
            for (int m = 0; m < 7; ++m)
                *(float4*)&wv[4 * m] = *(const float4*)&sy[j0 - 12 + 4 * m];
            float mv[4];
            #pragma unroll
            for (int e = 0; e < 4; ++e) {
                float acc = Hh[0] * wv[12 + e];
                #pragma unroll
                for (int k = 1; k <= WRAD + 1; ++k)
                    acc += Hh[k] * (wv[12 + e - k] + wv[12 + e + k]);
                mv[e] = acc;
            }
            *(float4*)&sm[j0] = make_float4(mv[0], mv[1], mv[2], mv[3]);
        } else {
            // edge path (only ~19 threads/block): exact f-based conv with all
            // boundary rules + image corrections, as in the verified kernel.
            const float M1  = sy[0]        - 2.0f * sy[1]        + sy[2];
            const float MS2 = sy[SLEN - 3] - 2.0f * sy[SLEN - 2] + sy[SLEN - 1];

            // ghost-point values (broadcast LDS reads)
            float v1 = 0.0f, vS2 = 0.0f;
            #pragma unroll
            for (int k = 1; k <= WRAD; ++k) {
                const int ja = 1 + k;                        // 2..9
                float fa = 6.0f * (sy[ja - 1] - 2.0f * sy[ja] + sy[ja + 1]);
                if (ja == 2) fa -= M1;
                v1 += G[k] * fa;
                const int jb = SLEN - 2 - k;                 // S-3 .. S-10
                float fb = 6.0f * (sy[jb - 1] - 2.0f * sy[jb] + sy[jb + 1]);
                if (jb == SLEN - 3) fb -= MS2;
                vS2 += G[k] * fb;
            }

            // guarded y window [j0-12, j0+16) (quads never partially OOB)
            float wv[28];
            #pragma unroll
            for (int m = 0; m < 7; ++m) {
                const int q = j0 - 12 + 4 * m;
                float4 v = make_float4(0.0f, 0.0f, 0.0f, 0.0f);
                if (q >= 0 && q <= SLEN - 4) v = *(const float4*)&sy[q];
                *(float4*)&wv[4 * m] = v;
            }
            // f[j0-8 .. j0+11] with boundary rules
            float fw[20];
            #pragma unroll
            for (int p = 0; p < 20; ++p) {
                const int jj = j0 + p - 8;
                float fv = 6.0f * (wv[p + 3] - 2.0f * wv[p + 4] + wv[p + 5]);
                if (jj < 2 || jj > SLEN - 3) fv = 0.0f;
                if (jj == 2)        fv -= M1;
                if (jj == SLEN - 3) fv -= MS2;
                fw[p] = fv;
            }
            float mv[4];
            #pragma unroll
            for (int e = 0; e < 4; ++e) {
                float acc = G[0] * fw[8 + e];
                #pragma unroll
                for (int k = 1; k <= WRAD; ++k)
                    acc += G[k] * (fw[8 + e - k] + fw[8 + e + k]);
                const int i = j0 + e;
                if (i >= 2 && i <= 34) {
                    float cc = v1 * exp2f((float)(i - 1) * log2r);
                    acc += (i & 1) ? -cc : cc;
                }
                if (i >= SLEN - 36 && i <= SLEN - 3) {
                    float cc = vS2 * exp2f((float)(SLEN - 2 - i) * log2r);
                    acc += (i & 1) ? cc : -cc;
                }
                mv[e] = acc;
            }
            if (j0 == 0)        { mv[1] = M1;  mv[0] = 2.0f * M1  - mv[2]; }
            if (j0 == SLEN - 4) { mv[2] = MS2; mv[3] = 2.0f * MS2 - mv[1]; }
            *(float4*)&sm[j0] = make_float4(mv[0], mv[1], mv[2], mv[3]);
        }
    }
    __syncthreads();

    // ---- pass D: warped evaluation, interleaved mapping j = t + 256*q ----
    // consecutive lanes -> consecutive idx (stride ~scale in [0.7,1.3])
    // => ~2 lanes/bank on all 4 scattered LDS reads (free), scalar coalesced stores.
    const float sc = scale[b];
    #pragma unroll
    for (int q = 0; q < 16; ++q) {
        const int j = t + BLK * q;
        float w = fminf((float)j * sc, (float)(SLEN - 1));
        int idx = (int)w;
        if (idx > SLEN - 2) idx = SLEN - 2;
        const float tt  = w - (float)idx;
        const float y0  = sy[idx];
        const float y1  = sy[idx + 1];
        const float m0  = sm[idx];
        const float m1v = sm[idx + 1];
        const float bb = (y1 - y0) - (2.0f * m0 + m1v) * (1.0f / 6.0f);
        const float cc = 0.5f * m0;
        const float dd = (m1v - m0) * (1.0f / 6.0f);
        const float res = y0 + tt * (bb + tt * (cc + tt * dd));
        __builtin_nontemporal_store(res, &o[j]);
    }
}

extern "C" void kernel_launch(void* const* d_in, const int* in_sizes, int n_in,
                              void* d_out, int out_size, void* d_ws, size_t ws_size,
                              hipStream_t stream) {
    const float* x     = (const float*)d_in[0];
    const float* scale = (const float*)d_in[1];
    const int*   mask  = (const int*)d_in[2];
    float*       out   = (float*)d_out;

    const int B     = in_sizes[1];            // 128
    const int total = in_sizes[0];            // B*C*S
    const int C     = total / (B * SLEN);     // 64
    const int nblk  = B * C;                  // 8192

    time_warp_kernel<<<nblk, BLK, 0, stream>>>(x, scale, mask, out, C);
}